// Round 3
// baseline (174.138 us; speedup 1.0000x reference)
//
#include <hip/hip_runtime.h>

#define BATCH   32768
#define DFEAT   768
#define NF      64     // fields
#define NE      12     // embedding dim
#define NTHR    256    // 4 waves
#define RPW     5      // rows per wave (12 e-lanes each, lanes 60..63 idle)
#define ROWS_PB (4*RPW)                            // 20 rows per block
#define NBLK    ((BATCH + ROWS_PB - 1) / ROWS_PB)  // 1639
#define PF      4      // x prefetch depth

// ---- pre-kernel: S[i][j] = (i!=j) ? 0.5*<V[i,j,:],V[j,i,:]> : 0  -> d_ws
__global__ void s_prep_kernel(const float* __restrict__ V, float* __restrict__ S) {
    const int idx = blockIdx.x * 256 + threadIdx.x;
    if (idx >= NF * NF) return;
    const int i = idx >> 6, j = idx & 63;
    const float4 a = *(const float4*)(V + (size_t)((i << 6) | j) * 4);
    const float4 b = *(const float4*)(V + (size_t)((j << 6) | i) * 4);
    S[idx] = (i == j) ? 0.0f
           : 0.5f * (a.x * b.x + a.y * b.y + a.z * b.z + a.w * b.w);
}

// Hot loop: acc[j] += S[i][j] * x[row][i][e].  S rows are fetched as float4
// (16 loads/i instead of 64) so even if the compiler emits per-lane VMEM
// instead of s_load, VMEM issue (≈64 cyc/i) stays well under FMA issue
// (128 cyc/i).  x streams with a 4-deep register prefetch.  No LDS in the
// hot loop; acc[64] in VGPRs (~90 total → 4+ waves/SIMD resident).
__global__ __launch_bounds__(NTHR, 4) void ffm_kernel(
    const float* __restrict__ x,
    const float* __restrict__ W,
    const float* __restrict__ bvec,
    const float* __restrict__ S,   // d_ws, [64][64], pre-halved, zero diag
    float* __restrict__ out)
{
    __shared__ float red[ROWS_PB][NE];

    const int tid  = threadIdx.x;
    const int w    = tid >> 6;
    const int lane = tid & 63;
    const int r5   = lane / NE;          // 0..5 (5 => idle lane)
    const int e    = lane - r5 * NE;     // 0..11
    const bool active = (r5 < RPW);

    int row = blockIdx.x * ROWS_PB + w * RPW + (active ? r5 : 0);
    if (row >= BATCH) row = BATCH - 1;   // clamped lanes never store

    const float* xr = x + (size_t)row * DFEAT + e;   // x[row][i][e] at xr[i*12]

    float acc[NF];
    #pragma unroll
    for (int j = 0; j < NF; ++j) acc[j] = 0.0f;

    float xb[PF];
    #pragma unroll
    for (int u = 0; u < PF; ++u) xb[u] = xr[u * NE];

    for (int i0 = 0; i0 < NF; i0 += PF) {
        #pragma unroll
        for (int u = 0; u < PF; ++u) {
            const int i  = i0 + u;
            const float xa = xb[u];
            const float4* s4 = (const float4*)(S + i * NF);
            #pragma unroll
            for (int c = 0; c < NF / 4; ++c) {
                const float4 sv = s4[c];
                acc[4*c+0] = fmaf(sv.x, xa, acc[4*c+0]);
                acc[4*c+1] = fmaf(sv.y, xa, acc[4*c+1]);
                acc[4*c+2] = fmaf(sv.z, xa, acc[4*c+2]);
                acc[4*c+3] = fmaf(sv.w, xa, acc[4*c+3]);
            }
            const int inext = (i + PF < NF) ? (i + PF) : (NF - 1);
            xb[u] = xr[inext * NE];
        }
    }

    // epilogue: p = sum_j x[row][j][e] * (acc[j] + W[j*12+e])
    float p = 0.0f;
    #pragma unroll
    for (int j = 0; j < NF; ++j)
        p = fmaf(xr[j * NE], acc[j] + W[j * NE + e], p);

    if (active) red[w * RPW + r5][e] = p;
    __syncthreads();

    if (tid < ROWS_PB) {
        const int orow = blockIdx.x * ROWS_PB + tid;
        if (orow < BATCH) {
            float s = 0.0f;
            #pragma unroll
            for (int q = 0; q < NE; ++q) s += red[tid][q];
            const float z = s + bvec[0];
            out[orow] = 1.0f / (1.0f + __expf(-z));
        }
    }
}

extern "C" void kernel_launch(void* const* d_in, const int* in_sizes, int n_in,
                              void* d_out, int out_size, void* d_ws, size_t ws_size,
                              hipStream_t stream) {
    const float* x  = (const float*)d_in[0];
    const float* W  = (const float*)d_in[1];  // [1,768]
    const float* bb = (const float*)d_in[2];  // [1]
    const float* V  = (const float*)d_in[3];  // [64,64,4]
    float* S   = (float*)d_ws;                // 16 KB scratch
    float* out = (float*)d_out;               // [32768]

    s_prep_kernel<<<dim3((NF * NF + 255) / 256), dim3(256), 0, stream>>>(V, S);
    ffm_kernel<<<dim3(NBLK), dim3(NTHR), 0, stream>>>(x, W, bb, S, out);
}

// Round 4
// 173.325 us; speedup vs baseline: 1.0047x; 1.0047x over previous
//
#include <hip/hip_runtime.h>

#define BATCH   32768
#define DFEAT   768
#define NF      64     // fields
#define NE      12     // embedding dim
#define NTHR    256    // 4 waves
#define RPW     5      // rows per wave (12 e-lanes each, lanes 60..63 idle)
#define ROWS_PB (4*RPW)                            // 20 rows per block
#define NBLK    ((BATCH + ROWS_PB - 1) / ROWS_PB)  // 1639
#define GRP     8      // rows per prefetch group (2 groups in flight)

// ---- pre-kernel: S[i][j] = (i!=j) ? 0.5*<V[i,j,:],V[j,i,:]> : 0  -> d_ws
__global__ void s_prep_kernel(const float* __restrict__ V, float* __restrict__ S) {
    const int idx = blockIdx.x * 256 + threadIdx.x;
    if (idx >= NF * NF) return;
    const int i = idx >> 6, j = idx & 63;
    const float4 a = *(const float4*)(V + (size_t)((i << 6) | j) * 4);
    const float4 b = *(const float4*)(V + (size_t)((j << 6) | i) * 4);
    S[idx] = (i == j) ? 0.0f
           : 0.5f * (a.x * b.x + a.y * b.y + a.z * b.z + a.w * b.w);
}

// one S-row sweep: acc[j] += S[i][j] * xa  (S address wave-uniform -> s_load)
__device__ __forceinline__ void fma_row(float (&acc)[NF], const float* __restrict__ Srow,
                                        const float xa) {
    #pragma unroll
    for (int c = 0; c < NF / 4; ++c) {
        const float4 sv = *(const float4*)(Srow + 4 * c);
        acc[4*c+0] = fmaf(sv.x, xa, acc[4*c+0]);
        acc[4*c+1] = fmaf(sv.y, xa, acc[4*c+1]);
        acc[4*c+2] = fmaf(sv.z, xa, acc[4*c+2]);
        acc[4*c+3] = fmaf(sv.w, xa, acc[4*c+3]);
    }
}

// Hot loop is pure v_fma(sgpr_S, vgpr_x, vgpr_acc).  x is double-buffered in
// registers, 8 rows per group, each group's loads issued back-to-back one
// full group (>=1024 cyc of FMA) before first use -> covers ~900-cyc HBM
// latency even at 1 wave/SIMD.  No LDS in the hot loop.
__global__ __launch_bounds__(NTHR, 4) void ffm_kernel(
    const float* __restrict__ x,
    const float* __restrict__ W,
    const float* __restrict__ bvec,
    const float* __restrict__ S,   // d_ws, [64][64], pre-halved, zero diag
    float* __restrict__ out)
{
    __shared__ float red[ROWS_PB][NE];

    const int tid  = threadIdx.x;
    const int w    = tid >> 6;
    const int lane = tid & 63;
    const int r5   = lane / NE;          // 0..5 (5 => idle lane)
    const int e    = lane - r5 * NE;     // 0..11
    const bool active = (r5 < RPW);

    int row = blockIdx.x * ROWS_PB + w * RPW + (active ? r5 : 0);
    if (row >= BATCH) row = BATCH - 1;   // clamped lanes never store

    const float* xr = x + (size_t)row * DFEAT + e;   // x[row][i][e] at xr[i*12]

    float acc[NF];
    #pragma unroll
    for (int j = 0; j < NF; ++j) acc[j] = 0.0f;

    float xa[GRP], xb[GRP];
    #pragma unroll
    for (int u = 0; u < GRP; ++u) xa[u] = xr[u * NE];          // group 0
    #pragma unroll
    for (int u = 0; u < GRP; ++u) xb[u] = xr[(GRP + u) * NE];  // group 1

    for (int i0 = 0; i0 < NF; i0 += 2 * GRP) {   // 4 iterations, rolled
        #pragma unroll
        for (int u = 0; u < GRP; ++u)
            fma_row(acc, S + (i0 + u) * NF, xa[u]);
        {   // prefetch group i0+16 (wraps to L1-hot rows 0..7 on last iter)
            const int ip = (i0 + 2 * GRP) & (NF - 1);
            #pragma unroll
            for (int u = 0; u < GRP; ++u) xa[u] = xr[(ip + u) * NE];
        }
        #pragma unroll
        for (int u = 0; u < GRP; ++u)
            fma_row(acc, S + (i0 + GRP + u) * NF, xb[u]);
        {   // prefetch group i0+24 (wraps to rows 8..15 on last iter)
            const int ip = (i0 + 3 * GRP) & (NF - 1);
            #pragma unroll
            for (int u = 0; u < GRP; ++u) xb[u] = xr[(ip + u) * NE];
        }
    }

    // epilogue: p = sum_j x[row][j][e] * (acc[j] + W[j*12+e])  (x reload L1-hot)
    float p = 0.0f;
    #pragma unroll
    for (int j = 0; j < NF; ++j)
        p = fmaf(xr[j * NE], acc[j] + W[j * NE + e], p);

    if (active) red[w * RPW + r5][e] = p;
    __syncthreads();

    if (tid < ROWS_PB) {
        const int orow = blockIdx.x * ROWS_PB + tid;
        if (orow < BATCH) {
            float s = 0.0f;
            #pragma unroll
            for (int q = 0; q < NE; ++q) s += red[tid][q];
            const float z = s + bvec[0];
            out[orow] = 1.0f / (1.0f + __expf(-z));
        }
    }
}

extern "C" void kernel_launch(void* const* d_in, const int* in_sizes, int n_in,
                              void* d_out, int out_size, void* d_ws, size_t ws_size,
                              hipStream_t stream) {
    const float* x  = (const float*)d_in[0];
    const float* W  = (const float*)d_in[1];  // [1,768]
    const float* bb = (const float*)d_in[2];  // [1]
    const float* V  = (const float*)d_in[3];  // [64,64,4]
    float* S   = (float*)d_ws;                // 16 KB scratch
    float* out = (float*)d_out;               // [32768]

    s_prep_kernel<<<dim3((NF * NF + 255) / 256), dim3(256), 0, stream>>>(V, S);
    ffm_kernel<<<dim3(NBLK), dim3(NTHR), 0, stream>>>(x, W, bb, S, out);
}

// Round 5
// 163.133 us; speedup vs baseline: 1.0675x; 1.0625x over previous
//
#include <hip/hip_runtime.h>
#include <hip/hip_bf16.h>

#define BATCH 32768
#define NF    64              // fields (K and N of the GEMM)
#define NE    12              // embedding dim
#define MB    16              // batch rows per block
#define MROWS (MB*NE)         // 192 M-rows per block
#define LSTR  68              // LDS f32 row stride (64 + 4 pad, keeps b128 alignment)
#define NBLK  (BATCH/MB)      // 2048

typedef __attribute__((ext_vector_type(8))) short short8;   // 8 bf16 = 4 VGPR
typedef __attribute__((ext_vector_type(4))) float float4v;

// d_ws layout: ShT bf16[64][64] @0 (8KB) | SlT bf16[64][64] @8KB | WT f32[12][64] @16KB
#define WS_SHT 0
#define WS_SLT 8192
#define WS_WT  16384

__device__ __forceinline__ short bfb(float v) {
    union { __hip_bfloat16 h; short s; } u;
    u.h = __float2bfloat16(v);
    return u.s;
}

// ---- prep: S = 0.5*<V[i,j],V[j,i]> (0 diag), split to bf16 hi/lo, TRANSPOSED
// [n=j][k=i] for B-operand b128 frag loads; WT[e][j] = W[j*12+e].
__global__ void prep_kernel(const float* __restrict__ V, const float* __restrict__ W,
                            unsigned short* __restrict__ ShT,
                            unsigned short* __restrict__ SlT,
                            float* __restrict__ WT) {
    const int idx = blockIdx.x * 256 + threadIdx.x;
    if (idx < NF * NF) {
        const int i = idx >> 6, j = idx & 63;
        const float4v a = *(const float4v*)(V + (size_t)((i << 6) | j) * 4);
        const float4v b = *(const float4v*)(V + (size_t)((j << 6) | i) * 4);
        const float s = (i == j) ? 0.0f
                      : 0.5f * (a.x * b.x + a.y * b.y + a.z * b.z + a.w * b.w);
        const __hip_bfloat16 sh = __float2bfloat16(s);
        const float shf = __bfloat162float(sh);
        union { __hip_bfloat16 h; unsigned short u; } uh, ul;
        uh.h = sh; ul.h = __float2bfloat16(s - shf);
        ShT[(j << 6) | i] = uh.u;
        SlT[(j << 6) | i] = ul.u;
    }
    if (idx < NF * NE) {               // 768
        const int j = idx / NE, e = idx - j * NE;
        WT[e * 64 + j] = W[idx];
    }
}

// Per block: 192x64 C-tile = A(192x64, bf16-split) x S(64x64, bf16-split),
// K=32x2 blocks x 3 products, fp32 acc.  Wave w owns m-subtiles 3w..3w+2.
__global__ __launch_bounds__(256, 3) void ffm_mfma(
    const float* __restrict__ x,
    const float* __restrict__ bvec,
    const unsigned short* __restrict__ ShT,
    const unsigned short* __restrict__ SlT,
    const float* __restrict__ WT,
    float* __restrict__ out)
{
    __shared__ float Xs[MROWS * LSTR];   // 51 KB, [(b,e)][i] fp32
    __shared__ float red[MROWS];

    const int tid  = threadIdx.x;
    const int w    = tid >> 6;
    const int lane = tid & 63;
    const int l15  = lane & 15;
    const int q    = lane >> 4;

    // ---- resident S fragments: B[k=q*8+j][n=l15] -> 16B from S^T row n
    short8 shf[4][2], slf[4][2];
    #pragma unroll
    for (int ns = 0; ns < 4; ++ns)
        #pragma unroll
        for (int kb = 0; kb < 2; ++kb) {
            const int off = ((ns << 4) + l15) * 64 + kb * 32 + q * 8;
            shf[ns][kb] = *(const short8*)(ShT + off);
            slf[ns][kb] = *(const short8*)(SlT + off);
        }

    // ---- stage x tile to LDS, transposed [(b,e)][i]
    const float4v* xg = (const float4v*)(x + (size_t)blockIdx.x * MB * (NF * NE));
    #pragma unroll
    for (int p = 0; p < 12; ++p) {
        const int fid = p * 256 + tid;        // 0..3071
        const int b   = fid / 192;
        const int c4  = fid - b * 192;
        const float4v v = xg[fid];
        const int d0 = c4 * 4;
        const int i0 = d0 / 12;
        const int e0 = d0 - i0 * 12;          // in {0,4,8}: 4 elems same i0
        float* dst = Xs + (b * NE + e0) * LSTR + i0;
        dst[0 * LSTR] = v.x; dst[1 * LSTR] = v.y;
        dst[2 * LSTR] = v.z; dst[3 * LSTR] = v.w;
    }
    __syncthreads();

    float4v acc[3][4];
    #pragma unroll
    for (int ms = 0; ms < 3; ++ms)
        #pragma unroll
        for (int ns = 0; ns < 4; ++ns)
            acc[ms][ns] = (float4v){0.f, 0.f, 0.f, 0.f};

    #pragma unroll
    for (int ms = 0; ms < 3; ++ms) {
        const int msg  = w * 3 + ms;           // global m-subtile 0..11
        const int mrow = (msg << 4) + l15;     // A row: m = lane&15
        float av[16];
        #pragma unroll
        for (int kb = 0; kb < 2; ++kb) {
            const float4v t0 = *(const float4v*)(Xs + mrow * LSTR + kb * 32 + q * 8);
            const float4v t1 = *(const float4v*)(Xs + mrow * LSTR + kb * 32 + q * 8 + 4);
            av[kb*8+0]=t0.x; av[kb*8+1]=t0.y; av[kb*8+2]=t0.z; av[kb*8+3]=t0.w;
            av[kb*8+4]=t1.x; av[kb*8+5]=t1.y; av[kb*8+6]=t1.z; av[kb*8+7]=t1.w;
        }
        short8 ah[2], al[2];
        #pragma unroll
        for (int kb = 0; kb < 2; ++kb)
            #pragma unroll
            for (int j = 0; j < 8; ++j) {
                const float v = av[kb * 8 + j];
                const __hip_bfloat16 h = __float2bfloat16(v);
                const float r = v - __bfloat162float(h);
                ah[kb][j] = bfb(v) , al[kb][j] = bfb(r);
            }
        #pragma unroll
        for (int ns = 0; ns < 4; ++ns) {
            float4v c = acc[ms][ns];
            c = __builtin_amdgcn_mfma_f32_16x16x32_bf16(ah[0], shf[ns][0], c, 0, 0, 0);
            c = __builtin_amdgcn_mfma_f32_16x16x32_bf16(ah[1], shf[ns][1], c, 0, 0, 0);
            c = __builtin_amdgcn_mfma_f32_16x16x32_bf16(al[0], shf[ns][0], c, 0, 0, 0);
            c = __builtin_amdgcn_mfma_f32_16x16x32_bf16(al[1], shf[ns][1], c, 0, 0, 0);
            c = __builtin_amdgcn_mfma_f32_16x16x32_bf16(ah[0], slf[ns][0], c, 0, 0, 0);
            c = __builtin_amdgcn_mfma_f32_16x16x32_bf16(ah[1], slf[ns][1], c, 0, 0, 0);
            acc[ms][ns] = c;
        }
    }

    // ---- epilogue: P[m] = sum_n A_f32[m][n]*(T[m][n] + WT[e(m)][n]); C/D row=q*4+reg
    #pragma unroll
    for (int ms = 0; ms < 3; ++ms) {
        const int msg = w * 3 + ms;
        #pragma unroll
        for (int rg = 0; rg < 4; ++rg) {
            const int m = (msg << 4) + (q << 2) + rg;
            const int e = m % NE;
            float p = 0.0f;
            #pragma unroll
            for (int ns = 0; ns < 4; ++ns) {
                const int n = (ns << 4) + l15;
                const float a  = Xs[m * LSTR + n];
                const float wt = WT[e * 64 + n];
                p = fmaf(a, acc[ms][ns][rg] + wt, p);
            }
            p += __shfl_xor(p, 1);
            p += __shfl_xor(p, 2);
            p += __shfl_xor(p, 4);
            p += __shfl_xor(p, 8);
            if (l15 == 0) red[m] = p;
        }
    }
    __syncthreads();

    if (tid < MB) {
        float s = 0.0f;
        #pragma unroll
        for (int e = 0; e < NE; ++e) s += red[tid * NE + e];
        const float z = s + bvec[0];
        out[blockIdx.x * MB + tid] = 1.0f / (1.0f + __expf(-z));
    }
}

extern "C" void kernel_launch(void* const* d_in, const int* in_sizes, int n_in,
                              void* d_out, int out_size, void* d_ws, size_t ws_size,
                              hipStream_t stream) {
    const float* x  = (const float*)d_in[0];
    const float* W  = (const float*)d_in[1];  // [1,768]
    const float* bb = (const float*)d_in[2];  // [1]
    const float* V  = (const float*)d_in[3];  // [64,64,4]
    unsigned short* ShT = (unsigned short*)((char*)d_ws + WS_SHT);
    unsigned short* SlT = (unsigned short*)((char*)d_ws + WS_SLT);
    float*          WT  = (float*)((char*)d_ws + WS_WT);
    float* out = (float*)d_out;

    prep_kernel<<<dim3(16), dim3(256), 0, stream>>>(V, W, ShT, SlT, WT);
    ffm_mfma<<<dim3(NBLK), dim3(256), 0, stream>>>(x, bb, ShT, SlT, WT, out);
}